// Round 1
// baseline (736.481 us; speedup 1.0000x reference)
//
#include <hip/hip_runtime.h>
#include <stdint.h>

#define HH 96
#define WW 96
#define NN (HH*WW)

// ws layout (bytes):
//   [0,      36864)  rank  int32[9216]
//   [36864,  73728)  perm  int32[9216]
//   [73728,  73732)  Mcnt  int32
//   [73792,  83008)  keep  u8[9216] (indexed by rank)
//   [131072, ...  )  mask  u64 rows, stride W=(M+63)>>6 words per row

__device__ __forceinline__ int coord1(int a) { return (10 * a + 1) / 3; }

// Counting rank: rank(k) = #{m: s_m > s_k} + #{m < k: s_m == s_k}
// == stable argsort(-score) position. Grid (36 k-tiles, 9 m-chunks).
__global__ void krank(const float* __restrict__ score, int* __restrict__ rank) {
    __shared__ float sm[1024];
    const int base = blockIdx.y * 1024;
    for (int t = threadIdx.x; t < 1024; t += 256) sm[t] = score[base + t];
    __syncthreads();
    const int k = blockIdx.x * 256 + threadIdx.x;
    const float sk = score[k];
    int cnt = 0;
    #pragma unroll 8
    for (int m = 0; m < 1024; ++m) {
        const float v = sm[m];
        const int gm = base + m;
        cnt += (v > sk) || (v == sk && gm < k);
    }
    atomicAdd(&rank[k], cnt);
}

__global__ void kscatter(const float* __restrict__ score, const int* __restrict__ rank,
                         int* __restrict__ perm, int* __restrict__ Mcnt) {
    const int k = blockIdx.x * 256 + threadIdx.x;
    const int r = rank[k];
    perm[r] = k;
    if (score[k] > 0.6f) atomicAdd(Mcnt, 1);
}

// Suppression matrix in rank space: bit (i,j) set iff j>i, j<M, inter(i,j) > 294
// (== iou > 0.5 exactly, since every box is 21x21 / area 441; see analysis).
__global__ void kmask(const int* __restrict__ perm, const int* __restrict__ Mcnt,
                      unsigned long long* __restrict__ mask) {
    const int M = *Mcnt;
    const int i = blockIdx.x;
    if (i >= M) return;
    const int W = (M + 63) >> 6;
    const int ki = perm[i];
    const int xi = coord1(ki % WW);
    const int yi = coord1(ki / WW);
    const int iters = (M + 255) >> 8;
    for (int it = 0; it < iters; ++it) {
        const int j = threadIdx.x + (it << 8);
        bool bit = false;
        if (j > i && j < M) {
            const int kj = perm[j];
            int dx = xi - coord1(kj % WW); dx = dx < 0 ? -dx : dx;
            int dy = yi - coord1(kj / WW); dy = dy < 0 ? -dy : dy;
            const int wx = 21 - dx, wy = 21 - dy;
            const int inter = (wx > 0 ? wx : 0) * (wy > 0 ? wy : 0);
            bit = inter > 294;
        }
        const unsigned long long word = __ballot(bit);
        if ((threadIdx.x & 63) == 0 && (j >> 6) < W)
            mask[(size_t)i * W + (j >> 6)] = word;
    }
}

// Sequential greedy NMS scan: single wave, remv bits register-resident
// (lane l owns words l, l+64, l+128), depth-8 row prefetch to hide L2 latency.
__global__ void kscan(const int* __restrict__ Mcnt,
                      const unsigned long long* __restrict__ mask,
                      unsigned char* __restrict__ keep) {
    const int l = threadIdx.x;
    const int M = *Mcnt;
    const int W = (M + 63) >> 6;
    unsigned long long r0 = 0ULL, r1 = 0ULL, r2 = 0ULL;
    unsigned long long pf[8][3];
    #pragma unroll
    for (int ph = 0; ph < 8; ++ph) {
        #pragma unroll
        for (int g = 0; g < 3; ++g) {
            const int w = l + 64 * g;
            pf[ph][g] = (ph < M && w < W) ? mask[(size_t)ph * W + w] : 0ULL;
        }
    }
    for (int base = 0; base < M; base += 8) {
        #pragma unroll
        for (int ph = 0; ph < 8; ++ph) {
            const int i = base + ph;
            if (i < M) {
                const int w = i >> 6;
                const int rg = w >> 6;           // uniform
                const unsigned long long rw = (rg == 0) ? r0 : (rg == 1 ? r1 : r2);
                const int src = w & 63;
                const unsigned int lo = __shfl((unsigned int)(rw & 0xffffffffu), src, 64);
                const unsigned int hi = __shfl((unsigned int)(rw >> 32), src, 64);
                const unsigned long long word = ((unsigned long long)hi << 32) | lo;
                const bool kept = ((word >> (i & 63)) & 1ULL) == 0ULL;  // wave-uniform
                if (kept) {
                    r0 |= pf[ph][0];
                    r1 |= pf[ph][1];
                    r2 |= pf[ph][2];
                }
                if (l == 0) keep[i] = kept ? 1 : 0;
                // prefetch row i+8 into this phase slot
                const int nr = i + 8;
                #pragma unroll
                for (int g = 0; g < 3; ++g) {
                    const int ww = l + 64 * g;
                    pf[ph][g] = (nr < M && ww < W) ? mask[(size_t)nr * W + ww] : 0ULL;
                }
            }
        }
    }
}

// Epilogue: only kept rows written; d_out pre-zeroed by memset.
__global__ void kout(const float* __restrict__ score, const float* __restrict__ reg,
                     const int* __restrict__ rank, const int* __restrict__ Mcnt,
                     const unsigned char* __restrict__ keep, float* __restrict__ out) {
    const int k = blockIdx.x * 256 + threadIdx.x;
    const int r = rank[k];
    const int M = *Mcnt;
    if (r >= M || !keep[r]) return;
    const int j = k % WW;
    const int i = k / WW;
    const float x1 = (float)coord1(j);
    const float y1 = (float)coord1(i);
    const float x2 = x1 + 20.0f;   // width exactly 21 for every box
    const float y2 = y1 + 20.0f;
    const float d0 = reg[k * 4 + 0];
    const float d1 = reg[k * 4 + 1];
    const float d2 = reg[k * 4 + 2];
    const float d3 = reg[k * 4 + 3];
    float* o = out + (size_t)r * 5;
    o[0] = x1 + d0 * 21.0f;
    o[1] = y1 + d1 * 21.0f;
    o[2] = x2 + d2 * 21.0f;
    o[3] = y2 + d3 * 21.0f;
    o[4] = score[k];
}

extern "C" void kernel_launch(void* const* d_in, const int* in_sizes, int n_in,
                              void* d_out, int out_size, void* d_ws, size_t ws_size,
                              hipStream_t stream) {
    const float* cls = (const float*)d_in[0];
    const float* reg = (const float*)d_in[1];
    float* out = (float*)d_out;
    char* ws = (char*)d_ws;
    int* rank = (int*)(ws);
    int* perm = (int*)(ws + 36864);
    int* Mcnt = (int*)(ws + 73728);
    unsigned char* keep = (unsigned char*)(ws + 73792);
    unsigned long long* mask = (unsigned long long*)(ws + 131072);

    hipMemsetAsync(d_out, 0, (size_t)out_size * sizeof(float), stream);
    hipMemsetAsync(ws, 0, 73732, stream);

    krank<<<dim3(36, 9), 256, 0, stream>>>(cls, rank);
    kscatter<<<36, 256, 0, stream>>>(cls, rank, perm, Mcnt);
    kmask<<<NN, 256, 0, stream>>>(perm, Mcnt, mask);
    kscan<<<1, 64, 0, stream>>>(Mcnt, mask, keep);
    kout<<<36, 256, 0, stream>>>(cls, reg, rank, Mcnt, keep, out);
}

// Round 2
// 639.831 us; speedup vs baseline: 1.1511x; 1.1511x over previous
//
#include <hip/hip_runtime.h>
#include <stdint.h>

#define HH 96
#define WW 96
#define NN (HH*WW)

// ws layout (bytes):
//   [0,      36864)  rank  int32[9216]
//   [36864,  73728)  perm  int32[9216]
//   [73728,  73732)  Mcnt  int32
//   [73792,  74944)  keptw u64[144] (kept bit per rank, chunked)
//   [131072, ...  )  mask  u64 rows, stride W=(M+63)>>6 words per row

__device__ __forceinline__ int coord1(int a) { return (10 * a + 1) / 3; }

__device__ __forceinline__ unsigned long long shfl64(unsigned long long v, int src) {
    unsigned int lo = __shfl((unsigned int)(v & 0xffffffffu), src, 64);
    unsigned int hi = __shfl((unsigned int)(v >> 32), src, 64);
    return ((unsigned long long)hi << 32) | lo;
}

// Counting rank: rank(k) = #{m: s_m > s_k} + #{m < k: s_m == s_k}
// == stable argsort(-score) position. Grid (36 k-tiles, 9 m-chunks).
__global__ void krank(const float* __restrict__ score, int* __restrict__ rank) {
    __shared__ float sm[1024];
    const int base = blockIdx.y * 1024;
    for (int t = threadIdx.x; t < 1024; t += 256) sm[t] = score[base + t];
    __syncthreads();
    const int k = blockIdx.x * 256 + threadIdx.x;
    const float sk = score[k];
    int cnt = 0;
    #pragma unroll 8
    for (int m = 0; m < 1024; ++m) {
        const float v = sm[m];
        const int gm = base + m;
        cnt += (v > sk) || (v == sk && gm < k);
    }
    atomicAdd(&rank[k], cnt);
}

__global__ void kscatter(const float* __restrict__ score, const int* __restrict__ rank,
                         int* __restrict__ perm, int* __restrict__ Mcnt) {
    const int k = blockIdx.x * 256 + threadIdx.x;
    const int r = rank[k];
    perm[r] = k;
    if (score[k] > 0.6f) atomicAdd(Mcnt, 1);
}

// Suppression matrix in rank space: bit (i,j) set iff j>i, j<M, inter(i,j) > 294
// (== iou > 0.5 exactly, since every box is 21x21 / area 441; see R0 analysis).
__global__ void kmask(const int* __restrict__ perm, const int* __restrict__ Mcnt,
                      unsigned long long* __restrict__ mask) {
    const int M = *Mcnt;
    const int i = blockIdx.x;
    if (i >= M) return;
    const int W = (M + 63) >> 6;
    const int ki = perm[i];
    const int xi = coord1(ki % WW);
    const int yi = coord1(ki / WW);
    const int iters = (M + 255) >> 8;
    for (int it = 0; it < iters; ++it) {
        const int j = threadIdx.x + (it << 8);
        bool bit = false;
        if (j > i && j < M) {
            const int kj = perm[j];
            int dx = xi - coord1(kj % WW); dx = dx < 0 ? -dx : dx;
            int dy = yi - coord1(kj / WW); dy = dy < 0 ? -dy : dy;
            const int wx = 21 - dx, wy = 21 - dy;
            const int inter = (wx > 0 ? wx : 0) * (wy > 0 ? wy : 0);
            bit = inter > 294;
        }
        const unsigned long long word = __ballot(bit);
        if ((threadIdx.x & 63) == 0 && (j >> 6) < W)
            mask[(size_t)i * W + (j >> 6)] = word;
    }
}

// Chunked greedy NMS: 64 rows resolved per step entirely in registers.
// Serial chain = W (~58) chunk steps, not M (~3700) row steps.
// Lane l owns remv words l, l+64, l+128. Diag tile for chunk c+1 prefetched
// during chunk c; only KEPT rows' full mask rows are fetched/OR'd.
__global__ void kscan(const int* __restrict__ Mcnt,
                      const unsigned long long* __restrict__ mask,
                      unsigned long long* __restrict__ keptw) {
    const int l = threadIdx.x;
    const int M = *Mcnt;
    const int W = (M + 63) >> 6;
    unsigned long long r0 = 0ULL, r1 = 0ULL, r2 = 0ULL;
    // prefetch diag tile word for chunk 0: lane l = row l, word 0
    unsigned long long Tn = (W > 0 && l < M) ? mask[(size_t)l * W + 0] : 0ULL;
    for (int c = 0; c < W; ++c) {
        const unsigned long long T = Tn;
        // prefetch next chunk's diag tile early (overlaps resolve+accumulate)
        const int nb = (c + 1) << 6;
        Tn = (c + 1 < W && nb + l < M) ? mask[(size_t)(nb + l) * W + (c + 1)] : 0ULL;
        // external suppression word for this chunk (from distributed remv)
        const int rg = c >> 6, src = c & 63;
        const unsigned long long rw = (rg == 0) ? r0 : (rg == 1 ? r1 : r2);
        unsigned long long s = shfl64(rw, src);
        const int base = c << 6;
        if (base + 64 > M) s |= (~0ULL) << (M - base);   // rows >= M invalid
        // in-register greedy resolve: iterate kept bits only (ctz skip)
        unsigned long long km = 0ULL;
        while (~s) {
            const int i = __builtin_ctzll(~s);
            km |= 1ULL << i;
            s |= shfl64(T, i) | (1ULL << i);
        }
        if (l == 0) keptw[c] = km;
        // accumulate kept rows' full mask rows into distributed remv
        unsigned long long t = km;
        while (t) {
            const int i = __builtin_ctzll(t);
            t &= t - 1;
            const size_t ro = (size_t)(base + i) * W;
            if (l < W)       r0 |= mask[ro + l];
            if (64 + l < W)  r1 |= mask[ro + 64 + l];
            if (128 + l < W) r2 |= mask[ro + 128 + l];
        }
    }
}

// Epilogue: every k has a unique rank r in [0,9216), so all out rows are
// covered — non-kept rows write zeros (no d_out memset needed).
__global__ void kout(const float* __restrict__ score, const float* __restrict__ reg,
                     const int* __restrict__ rank, const int* __restrict__ Mcnt,
                     const unsigned long long* __restrict__ keptw,
                     float* __restrict__ out) {
    const int k = blockIdx.x * 256 + threadIdx.x;
    const int r = rank[k];
    const int M = *Mcnt;
    const bool kp = (r < M) && ((keptw[r >> 6] >> (r & 63)) & 1ULL);
    const int j = k % WW;
    const int i = k / WW;
    const float x1 = (float)coord1(j);
    const float y1 = (float)coord1(i);
    const float d0 = reg[k * 4 + 0];
    const float d1 = reg[k * 4 + 1];
    const float d2 = reg[k * 4 + 2];
    const float d3 = reg[k * 4 + 3];
    float* o = out + (size_t)r * 5;
    o[0] = kp ? (x1 + d0 * 21.0f) : 0.0f;
    o[1] = kp ? (y1 + d1 * 21.0f) : 0.0f;
    o[2] = kp ? (x1 + 20.0f + d2 * 21.0f) : 0.0f;
    o[3] = kp ? (y1 + 20.0f + d3 * 21.0f) : 0.0f;
    o[4] = kp ? score[k] : 0.0f;
}

extern "C" void kernel_launch(void* const* d_in, const int* in_sizes, int n_in,
                              void* d_out, int out_size, void* d_ws, size_t ws_size,
                              hipStream_t stream) {
    const float* cls = (const float*)d_in[0];
    const float* reg = (const float*)d_in[1];
    float* out = (float*)d_out;
    char* ws = (char*)d_ws;
    int* rank = (int*)(ws);
    int* perm = (int*)(ws + 36864);
    int* Mcnt = (int*)(ws + 73728);
    unsigned long long* keptw = (unsigned long long*)(ws + 73792);
    unsigned long long* mask = (unsigned long long*)(ws + 131072);

    hipMemsetAsync(ws, 0, 73732, stream);   // rank + Mcnt

    krank<<<dim3(36, 9), 256, 0, stream>>>(cls, rank);
    kscatter<<<36, 256, 0, stream>>>(cls, rank, perm, Mcnt);
    kmask<<<NN, 256, 0, stream>>>(perm, Mcnt, mask);
    kscan<<<1, 64, 0, stream>>>(Mcnt, mask, keptw);
    kout<<<36, 256, 0, stream>>>(cls, reg, rank, Mcnt, keptw, out);
}

// Round 3
// 402.594 us; speedup vs baseline: 1.8293x; 1.5893x over previous
//
#include <hip/hip_runtime.h>
#include <stdint.h>

#define HH 96
#define WW 96
#define NN (HH*WW)

// ws layout (bytes):
//   [0,      36864)  rank  int32[9216]
//   [36864,  73728)  perm  int32[9216]
//   [73728,  73732)  Mcnt  int32
//   [73792,  74944)  keptw u64[144] (kept bit per rank, chunked)
//   [131072, ...  )  mask  u64 rows, stride W=(M+63)>>6 words per row

__device__ __forceinline__ int coord1(int a) { return (10 * a + 1) / 3; }

__device__ __forceinline__ unsigned long long shfl64(unsigned long long v, int src) {
    unsigned int lo = __shfl((unsigned int)(v & 0xffffffffu), src, 64);
    unsigned int hi = __shfl((unsigned int)(v >> 32), src, 64);
    return ((unsigned long long)hi << 32) | lo;
}

// Counting rank: rank(k) = #{m: s_m > s_k} + #{m < k: s_m == s_k}
// == stable argsort(-score) position. Grid (36 k-tiles, 9 m-chunks).
__global__ void krank(const float* __restrict__ score, int* __restrict__ rank) {
    __shared__ float sm[1024];
    const int base = blockIdx.y * 1024;
    for (int t = threadIdx.x; t < 1024; t += 256) sm[t] = score[base + t];
    __syncthreads();
    const int k = blockIdx.x * 256 + threadIdx.x;
    const float sk = score[k];
    int cnt = 0;
    #pragma unroll 8
    for (int m = 0; m < 1024; ++m) {
        const float v = sm[m];
        const int gm = base + m;
        cnt += (v > sk) || (v == sk && gm < k);
    }
    atomicAdd(&rank[k], cnt);
}

__global__ void kscatter(const float* __restrict__ score, const int* __restrict__ rank,
                         int* __restrict__ perm, int* __restrict__ Mcnt) {
    const int k = blockIdx.x * 256 + threadIdx.x;
    const int r = rank[k];
    perm[r] = k;
    if (score[k] > 0.6f) atomicAdd(Mcnt, 1);
}

// Suppression matrix in rank space: bit (i,j) set iff j>i, j<M, inter(i,j) > 294
// (== iou > 0.5 exactly, since every box is 21x21 / area 441; see R0 analysis).
__global__ void kmask(const int* __restrict__ perm, const int* __restrict__ Mcnt,
                      unsigned long long* __restrict__ mask) {
    const int M = *Mcnt;
    const int i = blockIdx.x;
    if (i >= M) return;
    const int W = (M + 63) >> 6;
    const int ki = perm[i];
    const int xi = coord1(ki % WW);
    const int yi = coord1(ki / WW);
    const int iters = (M + 255) >> 8;
    for (int it = 0; it < iters; ++it) {
        const int j = threadIdx.x + (it << 8);
        bool bit = false;
        if (j > i && j < M) {
            const int kj = perm[j];
            int dx = xi - coord1(kj % WW); dx = dx < 0 ? -dx : dx;
            int dy = yi - coord1(kj / WW); dy = dy < 0 ? -dy : dy;
            const int wx = 21 - dx, wy = 21 - dy;
            const int inter = (wx > 0 ? wx : 0) * (wy > 0 ? wy : 0);
            bit = inter > 294;
        }
        const unsigned long long word = __ballot(bit);
        if ((threadIdx.x & 63) == 0 && (j >> 6) < W)
            mask[(size_t)i * W + (j >> 6)] = word;
    }
}

// Chunked greedy NMS: 64 rows resolved per step in registers; kept-row mask
// accumulation batched 8-deep so load latency overlaps (R2 post-mortem: the
// one-load-per-kept-row waitcnt chain was 538us; 8 loads in flight / wait).
__global__ void kscan(const int* __restrict__ Mcnt,
                      const unsigned long long* __restrict__ mask,
                      unsigned long long* __restrict__ keptw) {
    const int l = threadIdx.x;
    const int M = *Mcnt;
    const int W = (M + 63) >> 6;
    unsigned long long r0 = 0ULL, r1 = 0ULL, r2 = 0ULL;
    // prefetch diag tile word for chunk 0: lane l = row l, word 0
    unsigned long long Tn = (W > 0 && l < M) ? mask[(size_t)l * W + 0] : 0ULL;
    for (int c = 0; c < W; ++c) {
        const unsigned long long T = Tn;
        // prefetch next chunk's diag tile early (overlaps resolve+accumulate)
        const int nb = (c + 1) << 6;
        Tn = (c + 1 < W && nb + l < M) ? mask[(size_t)(nb + l) * W + (c + 1)] : 0ULL;
        // external suppression word for this chunk (from distributed remv)
        const int rg = c >> 6, src = c & 63;
        const unsigned long long rw = (rg == 0) ? r0 : (rg == 1 ? r1 : r2);
        unsigned long long s = shfl64(rw, src);
        const int base = c << 6;
        if (base + 64 > M) s |= (~0ULL) << (M - base);   // rows >= M invalid
        // in-register greedy resolve: iterate kept bits only (ctz skip)
        unsigned long long km = 0ULL;
        while (~s) {
            const int i = __builtin_ctzll(~s);
            km |= 1ULL << i;
            s |= shfl64(T, i) | (1ULL << i);
        }
        if (l == 0) keptw[c] = km;
        // accumulate kept rows' mask rows into distributed remv, 8 loads/batch
        unsigned long long t = km;
        while (t) {
            size_t ro[8];
            int cnt = 0;
            #pragma unroll
            for (int u = 0; u < 8; ++u) {
                if (t) {
                    ro[u] = (size_t)(base + __builtin_ctzll(t)) * W;
                    t &= t - 1;
                    ++cnt;
                } else {
                    ro[u] = 0;
                }
            }
            unsigned long long a0[8], a1[8], a2[8];
            #pragma unroll
            for (int u = 0; u < 8; ++u) {
                a0[u] = (u < cnt && l < W)       ? mask[ro[u] + l]       : 0ULL;
                a1[u] = (u < cnt && 64 + l < W)  ? mask[ro[u] + 64 + l]  : 0ULL;
                a2[u] = (u < cnt && 128 + l < W) ? mask[ro[u] + 128 + l] : 0ULL;
            }
            r0 |= ((a0[0]|a0[1])|(a0[2]|a0[3])) | ((a0[4]|a0[5])|(a0[6]|a0[7]));
            r1 |= ((a1[0]|a1[1])|(a1[2]|a1[3])) | ((a1[4]|a1[5])|(a1[6]|a1[7]));
            r2 |= ((a2[0]|a2[1])|(a2[2]|a2[3])) | ((a2[4]|a2[5])|(a2[6]|a2[7]));
        }
    }
}

// Epilogue: every k has a unique rank r in [0,9216), so all out rows are
// covered — non-kept rows write zeros (no d_out memset needed).
__global__ void kout(const float* __restrict__ score, const float* __restrict__ reg,
                     const int* __restrict__ rank, const int* __restrict__ Mcnt,
                     const unsigned long long* __restrict__ keptw,
                     float* __restrict__ out) {
    const int k = blockIdx.x * 256 + threadIdx.x;
    const int r = rank[k];
    const int M = *Mcnt;
    const bool kp = (r < M) && ((keptw[r >> 6] >> (r & 63)) & 1ULL);
    const int j = k % WW;
    const int i = k / WW;
    const float x1 = (float)coord1(j);
    const float y1 = (float)coord1(i);
    const float d0 = reg[k * 4 + 0];
    const float d1 = reg[k * 4 + 1];
    const float d2 = reg[k * 4 + 2];
    const float d3 = reg[k * 4 + 3];
    float* o = out + (size_t)r * 5;
    o[0] = kp ? (x1 + d0 * 21.0f) : 0.0f;
    o[1] = kp ? (y1 + d1 * 21.0f) : 0.0f;
    o[2] = kp ? (x1 + 20.0f + d2 * 21.0f) : 0.0f;
    o[3] = kp ? (y1 + 20.0f + d3 * 21.0f) : 0.0f;
    o[4] = kp ? score[k] : 0.0f;
}

extern "C" void kernel_launch(void* const* d_in, const int* in_sizes, int n_in,
                              void* d_out, int out_size, void* d_ws, size_t ws_size,
                              hipStream_t stream) {
    const float* cls = (const float*)d_in[0];
    const float* reg = (const float*)d_in[1];
    float* out = (float*)d_out;
    char* ws = (char*)d_ws;
    int* rank = (int*)(ws);
    int* perm = (int*)(ws + 36864);
    int* Mcnt = (int*)(ws + 73728);
    unsigned long long* keptw = (unsigned long long*)(ws + 73792);
    unsigned long long* mask = (unsigned long long*)(ws + 131072);

    hipMemsetAsync(ws, 0, 73732, stream);   // rank + Mcnt

    krank<<<dim3(36, 9), 256, 0, stream>>>(cls, rank);
    kscatter<<<36, 256, 0, stream>>>(cls, rank, perm, Mcnt);
    kmask<<<NN, 256, 0, stream>>>(perm, Mcnt, mask);
    kscan<<<1, 64, 0, stream>>>(Mcnt, mask, keptw);
    kout<<<36, 256, 0, stream>>>(cls, reg, rank, Mcnt, keptw, out);
}

// Round 4
// 207.048 us; speedup vs baseline: 3.5570x; 1.9444x over previous
//
#include <hip/hip_runtime.h>
#include <stdint.h>

#define HH 96
#define WW 96
#define NN (HH*WW)

// ws layout (bytes):
//   [0,      331776)  rankp int32[9][9216]  (rank partial sums, no atomics)
//   [331776, 340992)  keep  u8[9216]

__device__ __forceinline__ int coord1(int a) { return (10 * a + 1) / 3; }

// Counting rank partials: block (x,y) counts, for each k in tile x, how many
// m in tile y beat it: (s_m > s_k) || (s_m == s_k && m < k). Sum over y in
// kout == stable argsort(-score) position. Direct store — no memset, no atomic.
__global__ void krank(const float* __restrict__ score, int* __restrict__ rankp) {
    __shared__ float sm[1024];
    const int base = blockIdx.y * 1024;
    for (int t = threadIdx.x; t < 1024; t += 256) sm[t] = score[base + t];
    __syncthreads();
    const int k = blockIdx.x * 256 + threadIdx.x;
    const float sk = score[k];
    int cnt = 0;
    #pragma unroll 8
    for (int m = 0; m < 1024; ++m) {
        const float v = sm[m];
        cnt += (v > sk) || (v == sk && (base + m) < k);
    }
    rankp[blockIdx.y * NN + k] = cnt;
}

// Greedy NMS as lexicographically-first MIS on the (local, degree<=12)
// suppression graph. Monotone fixpoint: KEPT when all higher-priority
// overlapping neighbors SUPP; SUPP when one such neighbor KEPT. Determined
// states are final+correct, so stale UNKNOWN reads only delay convergence
// (~10-15 rounds for random scores; capped at 64). Replaces the R3 serial
// rank-space scan (no mask matrix, no 944-load latency chain).
// Suppression test inter=(21-dx)(21-dy)>294 is exact iou>0.5 (R0 analysis);
// only offsets (0,±1),(0,±2),(±1,0),(±2,0),(±1,±1) can have an edge.
__global__ __launch_bounds__(1024) void knms(const float* __restrict__ cls,
                                             unsigned char* __restrict__ keep) {
    __shared__ float s[NN];
    __shared__ unsigned char st[NN];   // 0 unknown, 1 kept, 2 suppressed
    const int tid = threadIdx.x;
    for (int c = tid; c < NN; c += 1024) {
        const float v = cls[c];
        s[c] = v;
        st[c] = (v > 0.6f) ? 0 : 2;    // invalid cells never suppress: SUPP
    }
    __syncthreads();
    const int di[12] = {0,0, 0,0, -1,1, -2,2, -1,-1, 1,1};
    const int dj[12] = {-1,1,-2,2,  0,0,  0,0, -1, 1,-1,1};
    for (int round = 0; round < 64; ++round) {
        int any = 0;
        for (int c = tid; c < NN; c += 1024) {
            if (st[c] != 0) continue;
            const int i = c / WW, j = c % WW;
            const int xi = coord1(j), yi = coord1(i);
            const float sc = s[c];
            bool supp = false, unk = false;
            #pragma unroll
            for (int e = 0; e < 12; ++e) {
                const int ii = i + di[e], jj = j + dj[e];
                if (ii < 0 || ii >= HH || jj < 0 || jj >= WW) continue;
                int dx = xi - coord1(jj); dx = dx < 0 ? -dx : dx;
                int dy = yi - coord1(ii); dy = dy < 0 ? -dy : dy;
                if ((21 - dx) * (21 - dy) <= 294) continue;   // no edge
                const int v = ii * WW + jj;
                const float sv = s[v];
                if (!((sv > sc) || (sv == sc && v < c))) continue;  // lower prio
                const int svst = st[v];
                supp |= (svst == 1);
                unk  |= (svst == 0);
            }
            if (supp)      st[c] = 2;
            else if (!unk) st[c] = 1;
            else           any = 1;
        }
        if (__syncthreads_count(any) == 0) break;
    }
    for (int c = tid; c < NN; c += 1024) keep[c] = (st[c] == 1) ? 1 : 0;
}

// Epilogue: r = rank[k] (sum of 9 partials) is a permutation of [0,9216),
// so every output row is written exactly once — no d_out memset needed.
__global__ void kout(const float* __restrict__ score, const float* __restrict__ reg,
                     const int* __restrict__ rankp,
                     const unsigned char* __restrict__ keep,
                     float* __restrict__ out) {
    const int k = blockIdx.x * 256 + threadIdx.x;
    int r = 0;
    #pragma unroll
    for (int y = 0; y < 9; ++y) r += rankp[y * NN + k];
    const bool kp = keep[k] != 0;
    const int j = k % WW, i = k / WW;
    const float x1 = (float)coord1(j);
    const float y1 = (float)coord1(i);
    const float d0 = reg[k * 4 + 0];
    const float d1 = reg[k * 4 + 1];
    const float d2 = reg[k * 4 + 2];
    const float d3 = reg[k * 4 + 3];
    float* o = out + (size_t)r * 5;
    o[0] = kp ? (x1 + d0 * 21.0f) : 0.0f;
    o[1] = kp ? (y1 + d1 * 21.0f) : 0.0f;
    o[2] = kp ? (x1 + 20.0f + d2 * 21.0f) : 0.0f;
    o[3] = kp ? (y1 + 20.0f + d3 * 21.0f) : 0.0f;
    o[4] = kp ? score[k] : 0.0f;
}

extern "C" void kernel_launch(void* const* d_in, const int* in_sizes, int n_in,
                              void* d_out, int out_size, void* d_ws, size_t ws_size,
                              hipStream_t stream) {
    const float* cls = (const float*)d_in[0];
    const float* reg = (const float*)d_in[1];
    float* out = (float*)d_out;
    char* ws = (char*)d_ws;
    int* rankp = (int*)(ws);
    unsigned char* keep = (unsigned char*)(ws + 331776);

    krank<<<dim3(36, 9), 256, 0, stream>>>(cls, rankp);
    knms<<<1, 1024, 0, stream>>>(cls, keep);
    kout<<<36, 256, 0, stream>>>(cls, reg, rankp, keep, out);
}

// Round 5
// 117.581 us; speedup vs baseline: 6.2636x; 1.7609x over previous
//
#include <hip/hip_runtime.h>
#include <stdint.h>

#define HH 96
#define WW 96
#define NN (HH*WW)
#define NW 192   // bitmap words: 96 rows x 2 (128-bit padded rows, cols 96..127 dead)

// ws layout (bytes):
//   [0,      331776)  rankp int32[9][9216]  (rank partial sums)
//   [331776, 340992)  keep  u8[9216]

__device__ __forceinline__ int coord1(int a) { return (10 * a + 1) / 3; }

// Aligned shifted word: result bit b (cell col 64h+b) = src-row bit (64h+b+dj).
__device__ __forceinline__ unsigned long long shifted(unsigned long long A,
                                                      unsigned long long B,
                                                      int h, int dj) {
    const unsigned long long W0 = h ? B : A;
    if (dj == 0) return W0;
    if (dj > 0) {
        const unsigned long long Wr = h ? 0ULL : B;
        return (W0 >> dj) | (Wr << (64 - dj));
    }
    const int d = -dj;
    const unsigned long long Wl = h ? A : 0ULL;
    return (W0 << d) | (Wl >> (64 - d));
}

// Greedy NMS (== lexicographically-first MIS, R4-validated) as a bit-parallel
// monotone fixpoint. Score comparisons happen ONCE (ballot-built H masks);
// each round is shifted-bitmap logic on 192 u64 words (R4 post-mortem: byte
// sweeps redid 12 float compares/cell/round at LDS latency -> 127us).
__global__ __launch_bounds__(1024, 1) void knms(const float* __restrict__ cls,
                                                unsigned char* __restrict__ keep) {
    __shared__ float s[NN];                       // 36 KB
    __shared__ unsigned long long Hh[12][NW];     // 18 KB
    __shared__ unsigned long long K[NW], D[NW];   // 3 KB
    const int tid = threadIdx.x;
    const int lane = tid & 63;
    const int wave = tid >> 6;
    const int offs_di[12] = {0,0, 0,0, -1,1, -2,2, -1,-1, 1,1};
    const int offs_dj[12] = {-1,1,-2,2,  0,0,  0,0, -1, 1,-1,1};

    // stage scores (coalesced float4)
    for (int i = tid; i < NN/4; i += 1024)
        ((float4*)s)[i] = ((const float4*)cls)[i];
    __syncthreads();

    // Build H masks + K/D init via ballot. Word w: row w>>1, col base 64*(w&1);
    // lane l <-> col base+l (ballot bit l == lane l). 16 waves x 12 iters = 192.
    for (int it = 0; it < 12; ++it) {
        const int w = wave + (it << 4);
        const int row = w >> 1;
        const int col = ((w & 1) << 6) + lane;
        const bool incell = (col < WW);
        const int c = row * WW + col;
        const float sc = incell ? s[c] : 0.0f;
        const int xi = coord1(col), yi = coord1(row);
        const unsigned long long dinit = __ballot(!incell || !(sc > 0.6f));
        if (lane == 0) { D[w] = dinit; K[w] = 0ULL; }
        #pragma unroll
        for (int e = 0; e < 12; ++e) {
            const int ii = row + offs_di[e], jj = col + offs_dj[e];
            bool hp = false;
            if (incell && ii >= 0 && ii < HH && jj >= 0 && jj < WW) {
                int dx = xi - coord1(jj); dx = dx < 0 ? -dx : dx;
                int dy = yi - coord1(ii); dy = dy < 0 ? -dy : dy;
                if ((21 - dx) * (21 - dy) > 294) {   // exact iou>0.5 (R0 analysis)
                    const int v = ii * WW + jj;
                    const float sv = s[v];
                    hp = (sv > sc) || (sv == sc && v < c);
                }
            }
            const unsigned long long m = __ballot(hp);
            if (lane == 0) Hh[e][w] = m;
        }
    }
    __syncthreads();

    // Fixpoint: thread w<192 owns word w. Stale/torn u64 reads safe (monotone).
    unsigned long long Hr[12];
    const int w = tid;
    int row = 0, h = 0;
    if (w < NW) {
        #pragma unroll
        for (int e = 0; e < 12; ++e) Hr[e] = Hh[e][w];
        row = w >> 1; h = w & 1;
    }
    for (int round = 0; round < 256; ++round) {
        int undet = 0;
        if (w < NW) {
            const unsigned long long Dw = D[w];
            if (~Dw) {
                unsigned long long KA[5], KB[5], DA[5], DB[5];
                #pragma unroll
                for (int q = 0; q < 5; ++q) {
                    const int rr = row + q - 2;
                    const bool ok = (rr >= 0) && (rr < HH);
                    KA[q] = ok ? K[rr*2]   : 0ULL;
                    KB[q] = ok ? K[rr*2+1] : 0ULL;
                    DA[q] = ok ? D[rr*2]   : 0ULL;
                    DB[q] = ok ? D[rr*2+1] : 0ULL;
                }
                unsigned long long supp = 0ULL, alldet = ~0ULL;
                #pragma unroll
                for (int e = 0; e < 12; ++e) {
                    const int q = offs_di[e] + 2;
                    const int dj = offs_dj[e];
                    supp   |=  Hr[e] & shifted(KA[q], KB[q], h, dj);
                    alldet &= ~Hr[e] | shifted(DA[q], DB[q], h, dj);
                }
                const unsigned long long U = ~Dw;
                const unsigned long long newK = K[w] | (U & alldet & ~supp);
                const unsigned long long newD = Dw | (U & (supp | alldet));
                K[w] = newK; D[w] = newD;
                undet = ((~newD) != 0ULL) ? 1 : 0;
            }
        }
        if (__syncthreads_count(undet) == 0) break;
    }
    // export keep bytes
    for (int c = tid; c < NN; c += 1024) {
        const int r = c / WW, col = c % WW;
        keep[c] = (unsigned char)((K[r*2 + (col >> 6)] >> (col & 63)) & 1ULL);
    }
}

// Counting rank partials (R4 structure, b128 LDS broadcast reads).
__global__ void krank(const float* __restrict__ score, int* __restrict__ rankp) {
    __shared__ float4 sm[256];
    const int base = blockIdx.y * 1024;
    sm[threadIdx.x & 255] = ((const float4*)(score + base))[threadIdx.x & 255];
    __syncthreads();
    const int k = blockIdx.x * 256 + threadIdx.x;
    const float sk = score[k];
    int cnt = 0;
    #pragma unroll 4
    for (int m4 = 0; m4 < 256; ++m4) {
        const float4 v = sm[m4];
        const int gm = base + (m4 << 2);
        cnt += (v.x > sk) || (v.x == sk && (gm + 0) < k);
        cnt += (v.y > sk) || (v.y == sk && (gm + 1) < k);
        cnt += (v.z > sk) || (v.z == sk && (gm + 2) < k);
        cnt += (v.w > sk) || (v.w == sk && (gm + 3) < k);
    }
    rankp[blockIdx.y * NN + k] = cnt;
}

// Epilogue: r = rank[k] is a permutation of [0,9216) — every output row
// written exactly once, no d_out memset needed.
__global__ void kout(const float* __restrict__ score, const float* __restrict__ reg,
                     const int* __restrict__ rankp,
                     const unsigned char* __restrict__ keep,
                     float* __restrict__ out) {
    const int k = blockIdx.x * 256 + threadIdx.x;
    int r = 0;
    #pragma unroll
    for (int y = 0; y < 9; ++y) r += rankp[y * NN + k];
    const bool kp = keep[k] != 0;
    const int j = k % WW, i = k / WW;
    const float x1 = (float)coord1(j);
    const float y1 = (float)coord1(i);
    const float d0 = reg[k * 4 + 0];
    const float d1 = reg[k * 4 + 1];
    const float d2 = reg[k * 4 + 2];
    const float d3 = reg[k * 4 + 3];
    float* o = out + (size_t)r * 5;
    o[0] = kp ? (x1 + d0 * 21.0f) : 0.0f;
    o[1] = kp ? (y1 + d1 * 21.0f) : 0.0f;
    o[2] = kp ? (x1 + 20.0f + d2 * 21.0f) : 0.0f;
    o[3] = kp ? (y1 + 20.0f + d3 * 21.0f) : 0.0f;
    o[4] = kp ? score[k] : 0.0f;
}

extern "C" void kernel_launch(void* const* d_in, const int* in_sizes, int n_in,
                              void* d_out, int out_size, void* d_ws, size_t ws_size,
                              hipStream_t stream) {
    const float* cls = (const float*)d_in[0];
    const float* reg = (const float*)d_in[1];
    float* out = (float*)d_out;
    char* ws = (char*)d_ws;
    int* rankp = (int*)(ws);
    unsigned char* keep = (unsigned char*)(ws + 331776);

    krank<<<dim3(36, 9), 256, 0, stream>>>(cls, rankp);
    knms<<<1, 1024, 0, stream>>>(cls, keep);
    kout<<<36, 256, 0, stream>>>(cls, reg, rankp, keep, out);
}